// Round 8
// baseline (546.734 us; speedup 1.0000x reference)
//
#include <hip/hip_runtime.h>
#include <math.h>

#define N_NODES 20000
#define N_EDGES 320000
#define N_GRAPHS 64
#define D_IN 1280
#define D_H 512
#define D_FC 1024
#define OUT_DIMS 5000
#define BKT_CAP 64  // max degree capacity (true max ~38 for Poisson(16) over 20k nodes)
#define PSPLIT 8    // pool node-split factor

typedef unsigned short ushort_t;
typedef short bf16x8 __attribute__((ext_vector_type(8)));
typedef float f32x4 __attribute__((ext_vector_type(4)));

__device__ __forceinline__ ushort_t f2b(float x) {
    unsigned u = __float_as_uint(x);
    unsigned r = (u + 0x7FFFu + ((u >> 16) & 1u)) >> 16;  // RNE
    return (ushort_t)r;
}

// packed f32x2 -> bf16x2, RNE (bit-identical to f2b for normal values)
__device__ __forceinline__ unsigned cvt_pk(float lo, float hi) {
    unsigned r;
    asm("v_cvt_pk_bf16_f32 %0, %1, %2" : "=v"(r) : "v"(lo), "v"(hi));
    return r;
}

// ============ direct-load 1-wave 64x64 bf16 MFMA GEMM (NO LDS) ============
// Key fact: for mfma_f32_16x16x32_bf16, lane (lo,quad) needs A[m0+lo][k0+quad*8..+7]
// = 16 CONTIGUOUS bytes of the row-major operand -> per-lane global dwordx4 IS the
// frag load. LDS staging gave zero dedup (each chunk feeds one frag) and cost a
// ~220cyc round-trip per iter. B (1.3MB) is L2-resident; A panels are shared by
// the 8 same-XCD col-tile blocks concurrently (hot window ~1.6MB << 4MB L2).
// 2-deep register pipeline, static indexing, no barriers, no manual waitcnt.
// Grid: 2504 = 313 row-tiles x 8 col-tiles; XCD swizzle v=(bid&7)*313+(bid>>3).
__global__ __launch_bounds__(64) void gemm_dir_bf16(const ushort_t* __restrict__ A,
                                                    const ushort_t* __restrict__ BT,
                                                    ushort_t* __restrict__ C,
                                                    int M, int N, int K) {
    const int lane = threadIdx.x;
    const int lo = lane & 15, quad = lane >> 4;
    const int bid = blockIdx.x;
    const int v = (bid & 7) * 313 + (bid >> 3);  // bijective: 2504 = 8*313
    const int rowBase = (v >> 3) * 64;
    const int colBase = (v & 7) * 64;

    const ushort_t* pa[4];
    const ushort_t* pb[4];
#pragma unroll
    for (int i = 0; i < 4; ++i) {
        int r = rowBase + i * 16 + lo;
        if (r >= M) r = M - 1;  // clamped rows computed but never stored
        pa[i] = A + (size_t)r * K + quad * 8;
        pb[i] = BT + (size_t)(colBase + i * 16 + lo) * K + quad * 8;  // N=512 exact
    }

    f32x4 acc[4][4] = {};
    const int NK = K >> 5;  // even (16 or 40)

    bf16x8 a0[4], b0[4], a1[4], b1[4];
#pragma unroll
    for (int i = 0; i < 4; ++i) {  // preload k=0 (offset 0)
        a0[i] = *(const bf16x8*)(pa[i]);
        b0[i] = *(const bf16x8*)(pb[i]);
    }

    for (int kk = 0; kk < NK; kk += 2) {
#pragma unroll
        for (int i = 0; i < 4; ++i) {  // load k=kk+1 (offset 32)
            a1[i] = *(const bf16x8*)(pa[i] + 32);
            b1[i] = *(const bf16x8*)(pb[i] + 32);
        }
#pragma unroll
        for (int i = 0; i < 4; ++i)
#pragma unroll
            for (int j = 0; j < 4; ++j)
                acc[i][j] = __builtin_amdgcn_mfma_f32_16x16x32_bf16(a0[i], b0[j], acc[i][j], 0, 0, 0);
#pragma unroll
        for (int i = 0; i < 4; ++i) { pa[i] += 64; pb[i] += 64; }
        if (kk + 2 < NK) {
#pragma unroll
            for (int i = 0; i < 4; ++i) {  // load k=kk+2 (new offset 0)
                a0[i] = *(const bf16x8*)(pa[i]);
                b0[i] = *(const bf16x8*)(pb[i]);
            }
        }
#pragma unroll
        for (int i = 0; i < 4; ++i)
#pragma unroll
            for (int j = 0; j < 4; ++j)
                acc[i][j] = __builtin_amdgcn_mfma_f32_16x16x32_bf16(a1[i], b1[j], acc[i][j], 0, 0, 0);
    }

#pragma unroll
    for (int i = 0; i < 4; ++i) {
        int row0 = rowBase + i * 16 + quad * 4;
#pragma unroll
        for (int j = 0; j < 4; ++j) {
            int col = colBase + j * 16 + lo;
            if (col >= N) continue;
#pragma unroll
            for (int r = 0; r < 4; ++r) {
                int row = row0 + r;
                if (row < M) C[(size_t)row * N + col] = f2b(acc[i][j][r]);
            }
        }
    }
}

// ============ direct-load GEMM, A consumed as f32 (conv1) ============
// Per frag: load 32B f32 (2 float4) -> 4x cvt_pk -> bf16x8. Kills the separate
// x->bf16 conversion pass entirely (x read once here as f32).
__global__ __launch_bounds__(64) void gemm_dir_af32(const float* __restrict__ A,
                                                    const ushort_t* __restrict__ BT,
                                                    ushort_t* __restrict__ C,
                                                    int M, int N, int K) {
    const int lane = threadIdx.x;
    const int lo = lane & 15, quad = lane >> 4;
    const int bid = blockIdx.x;
    const int v = (bid & 7) * 313 + (bid >> 3);
    const int rowBase = (v >> 3) * 64;
    const int colBase = (v & 7) * 64;

    const float* pa[4];
    const ushort_t* pb[4];
#pragma unroll
    for (int i = 0; i < 4; ++i) {
        int r = rowBase + i * 16 + lo;
        if (r >= M) r = M - 1;
        pa[i] = A + (size_t)r * K + quad * 8;
        pb[i] = BT + (size_t)(colBase + i * 16 + lo) * K + quad * 8;
    }

#define LDA(dst, off)                                                     \
    {                                                                     \
        _Pragma("unroll") for (int i = 0; i < 4; ++i) {                   \
            float4 f0 = *(const float4*)(pa[i] + (off));                  \
            float4 f1 = *(const float4*)(pa[i] + (off) + 4);              \
            uint4 u;                                                     \
            u.x = cvt_pk(f0.x, f0.y); u.y = cvt_pk(f0.z, f0.w);          \
            u.z = cvt_pk(f1.x, f1.y); u.w = cvt_pk(f1.z, f1.w);          \
            dst[i] = *(bf16x8*)&u;                                       \
        }                                                                 \
    }

    f32x4 acc[4][4] = {};
    const int NK = K >> 5;  // 40 for D_IN (even)

    bf16x8 a0[4], b0[4], a1[4], b1[4];
    LDA(a0, 0);
#pragma unroll
    for (int i = 0; i < 4; ++i) b0[i] = *(const bf16x8*)(pb[i]);

    for (int kk = 0; kk < NK; kk += 2) {
        LDA(a1, 32);
#pragma unroll
        for (int i = 0; i < 4; ++i) b1[i] = *(const bf16x8*)(pb[i] + 32);
#pragma unroll
        for (int i = 0; i < 4; ++i)
#pragma unroll
            for (int j = 0; j < 4; ++j)
                acc[i][j] = __builtin_amdgcn_mfma_f32_16x16x32_bf16(a0[i], b0[j], acc[i][j], 0, 0, 0);
#pragma unroll
        for (int i = 0; i < 4; ++i) { pa[i] += 64; pb[i] += 64; }
        if (kk + 2 < NK) {
            LDA(a0, 0);
#pragma unroll
            for (int i = 0; i < 4; ++i) b0[i] = *(const bf16x8*)(pb[i]);
        }
#pragma unroll
        for (int i = 0; i < 4; ++i)
#pragma unroll
            for (int j = 0; j < 4; ++j)
                acc[i][j] = __builtin_amdgcn_mfma_f32_16x16x32_bf16(a1[i], b1[j], acc[i][j], 0, 0, 0);
    }
#undef LDA

#pragma unroll
    for (int i = 0; i < 4; ++i) {
        int row0 = rowBase + i * 16 + quad * 4;
#pragma unroll
        for (int j = 0; j < 4; ++j) {
            int col = colBase + j * 16 + lo;
            if (col >= N) continue;
#pragma unroll
            for (int r = 0; r < 4; ++r) {
                int row = row0 + r;
                if (row < M) C[(size_t)row * N + col] = f2b(acc[i][j][r]);
            }
        }
    }
}

// ================= fused prep kernel =================
// blocks [0,5):     zero cursor (20000 ints)
// blocks [5,645):   W1 (1280x512) transpose+cvt -> w1t (LDS 32x32 tiles)
// blocks [645,901): W2 (512x512)  transpose+cvt -> w2t
// block  901:       graph_bounds
#define PREP_ZB 5
#define PREP_T1 640
#define PREP_T2 256
#define PREP_NBLK (PREP_ZB + PREP_T1 + PREP_T2 + 1)

__global__ __launch_bounds__(256) void prep_all(const float* __restrict__ W1src, ushort_t* __restrict__ w1t,
                                                const float* __restrict__ W2src, ushort_t* __restrict__ w2t,
                                                int* __restrict__ zbase,  // cursor
                                                const int* __restrict__ batch, int* __restrict__ gstart) {
    __shared__ float tile[32][33];
    int b = blockIdx.x;
    const int t = threadIdx.x;

    if (b < PREP_ZB) {  // zero 20000 ints
        int i = b * 256 + t;
        if (i < 1250) {
            int4* p = (int4*)zbase + (size_t)i * 4;
            int4 z = {0, 0, 0, 0};
            p[0] = z; p[1] = z; p[2] = z; p[3] = z;
        }
        return;
    }
    b -= PREP_ZB;

    if (b < PREP_T1 + PREP_T2) {  // tiled transpose + cvt
        const float* W;
        ushort_t* WT;
        int K, N, tb;
        if (b < PREP_T1) { W = W1src; WT = w1t; K = D_IN; N = D_H; tb = b; }
        else             { W = W2src; WT = w2t; K = D_H;  N = D_H; tb = b - PREP_T1; }
        const int ntn = N >> 5;
        const int kt = tb / ntn, nt = tb - kt * ntn;
        const int tx = t & 31, ty = t >> 5;
#pragma unroll
        for (int it = 0; it < 4; ++it) {
            int k = kt * 32 + ty + it * 8;
            tile[ty + it * 8][tx] = W[(size_t)k * N + nt * 32 + tx];
        }
        __syncthreads();
#pragma unroll
        for (int it = 0; it < 4; ++it) {
            int n = nt * 32 + ty + it * 8;
            WT[(size_t)n * K + kt * 32 + tx] = f2b(tile[tx][ty + it * 8]);
        }
        return;
    }

    // graph_bounds
    if (t <= N_GRAPHS) {
        int lo = 0, hi = N_NODES;
        while (lo < hi) {
            int mid = (lo + hi) >> 1;
            if (batch[mid] < t) lo = mid + 1; else hi = mid;
        }
        gstart[t] = lo;
    }
}

// ---------------- bucket CSR (no scan): col[d*64+p] ----------------
__global__ void fill_bucket(const int* __restrict__ src, const int* __restrict__ dst,
                            int* __restrict__ cursor, int* __restrict__ col) {
    int e = blockIdx.x * blockDim.x + threadIdx.x;
    if (e < N_EDGES) {
        int d = dst[e];
        int p = atomicAdd(cursor + d, 1);
        if (p < BKT_CAP) col[(d << 6) + p] = src[e];
    }
}

// dinv = rsqrt(true_degree + 1); cursor holds true degree after fill_bucket
__global__ void compute_dinv(const int* __restrict__ deg, float* __restrict__ dinv) {
    int v = blockIdx.x * blockDim.x + threadIdx.x;
    if (v < N_NODES) dinv[v] = rsqrtf((float)deg[v] + 1.0f);
}

// ---------------- fp32 split-K tiled GEMM (FC head) ----------------
__global__ __launch_bounds__(256) void gemm_splitk(const float* __restrict__ A,
                                                   const float* __restrict__ B,
                                                   float* __restrict__ P,
                                                   int M, int N, int K, int KC) {
    __shared__ float As[16][64];
    __shared__ float Bs[16][64];
    const int t = threadIdx.x;
    const int tx = t & 15, ty = t >> 4;
    const int rowBase = blockIdx.y * 64;
    const int colBase = blockIdx.x * 64;
    const int kbeg = blockIdx.z * KC;
    const int kend = kbeg + KC;
    float acc[4][4] = {};
    for (int k0 = kbeg; k0 < kend; k0 += 16) {
#pragma unroll
        for (int i = 0; i < 4; ++i) {
            int idx = t + i * 256;
            int row = idx >> 4, kk = idx & 15;
            int gr = rowBase + row;
            As[kk][row] = (gr < M) ? A[(size_t)gr * K + k0 + kk] : 0.f;
        }
#pragma unroll
        for (int i = 0; i < 4; ++i) {
            int idx = t + i * 256;
            int kk = idx >> 6, col = idx & 63;
            int gc = colBase + col;
            Bs[kk][col] = (gc < N) ? B[(size_t)(k0 + kk) * N + gc] : 0.f;
        }
        __syncthreads();
#pragma unroll
        for (int kk = 0; kk < 16; ++kk) {
            float a[4], bb[4];
#pragma unroll
            for (int i = 0; i < 4; ++i) a[i] = As[kk][ty * 4 + i];
#pragma unroll
            for (int j = 0; j < 4; ++j) bb[j] = Bs[kk][tx * 4 + j];
#pragma unroll
            for (int i = 0; i < 4; ++i)
#pragma unroll
                for (int j = 0; j < 4; ++j) acc[i][j] = fmaf(a[i], bb[j], acc[i][j]);
        }
        __syncthreads();
    }
    float* Pz = P + (size_t)blockIdx.z * M * N;
#pragma unroll
    for (int i = 0; i < 4; ++i) {
        int gr = rowBase + ty * 4 + i;
        if (gr >= M) continue;
#pragma unroll
        for (int j = 0; j < 4; ++j) {
            int gc = colBase + tx * 4 + j;
            if (gc < N) Pz[(size_t)gr * N + gc] = acc[i][j];
        }
    }
}

__global__ void reduce_bias_relu(const float* __restrict__ P, const float* __restrict__ b,
                                 float* __restrict__ out, int total, int N, int S) {
    int i = blockIdx.x * blockDim.x + threadIdx.x;
    if (i >= total) return;
    float s = 0.f;
    for (int z = 0; z < S; ++z) s += P[(size_t)z * total + i];
    out[i] = fmaxf(s + b[i % N], 0.f);
}

__global__ void reduce_bn_sigmoid(const float* __restrict__ P, const float* __restrict__ b2,
                                  const float* __restrict__ gamma, const float* __restrict__ beta,
                                  float* __restrict__ out, int S) {
    int i = blockIdx.x * blockDim.x + threadIdx.x;
    if (i >= N_GRAPHS * OUT_DIMS) return;
    int c = i % OUT_DIMS;
    float s = 0.f;
    for (int z = 0; z < S; ++z) s += P[(size_t)z * N_GRAPHS * OUT_DIMS + i];
    const float sc = 0.9999950000374997f;  // 1/sqrt(1+1e-5)
    float zz = (s + b2[c]) * (gamma[c] * sc) + beta[c];
    out[i] = 1.f / (1.f + expf(-zz));
}

// ---------------- bf16 gather-aggregate ----------------
__device__ __forceinline__ void bf8_fma(uint4 v, float c, float* acc) {
    unsigned a[4] = {v.x, v.y, v.z, v.w};
#pragma unroll
    for (int i = 0; i < 4; ++i) {
        float lo = __uint_as_float(a[i] << 16);
        float hi = __uint_as_float(a[i] & 0xFFFF0000u);
        acc[2 * i]     = fmaf(lo, c, acc[2 * i]);
        acc[2 * i + 1] = fmaf(hi, c, acc[2 * i + 1]);
    }
}

__device__ __forceinline__ void agg_node_bf16(const ushort_t* __restrict__ H,
                                              const int* __restrict__ deg,
                                              const int* __restrict__ col,
                                              const float* __restrict__ dinv,
                                              const float* __restrict__ bias,
                                              int v, int f, float* r) {
    const int beg = v << 6;
    int d = deg[v]; if (d > BKT_CAP) d = BKT_CAP;
    const int end = beg + d;
    const float dv = dinv[v];
    float acc[8] = {};
    int j = beg;
    for (; j + 7 < end; j += 8) {
        int s[8];
#pragma unroll
        for (int u = 0; u < 8; ++u) s[u] = col[j + u];
        float c[8];
#pragma unroll
        for (int u = 0; u < 8; ++u) c[u] = dinv[s[u]] * dv;
        uint4 h[8];
#pragma unroll
        for (int u = 0; u < 8; ++u) h[u] = *(const uint4*)(H + (size_t)s[u] * D_H + f);
#pragma unroll
        for (int u = 0; u < 8; ++u) bf8_fma(h[u], c[u], acc);
    }
    for (; j + 3 < end; j += 4) {
        int s0 = col[j], s1 = col[j + 1], s2 = col[j + 2], s3 = col[j + 3];
        float c0 = dinv[s0] * dv, c1 = dinv[s1] * dv;
        float c2 = dinv[s2] * dv, c3 = dinv[s3] * dv;
        uint4 h0 = *(const uint4*)(H + (size_t)s0 * D_H + f);
        uint4 h1 = *(const uint4*)(H + (size_t)s1 * D_H + f);
        uint4 h2 = *(const uint4*)(H + (size_t)s2 * D_H + f);
        uint4 h3 = *(const uint4*)(H + (size_t)s3 * D_H + f);
        bf8_fma(h0, c0, acc);
        bf8_fma(h1, c1, acc);
        bf8_fma(h2, c2, acc);
        bf8_fma(h3, c3, acc);
    }
    for (; j < end; ++j) {
        int s0 = col[j];
        float c0 = dinv[s0] * dv;
        uint4 h0 = *(const uint4*)(H + (size_t)s0 * D_H + f);
        bf8_fma(h0, c0, acc);
    }
    uint4 hv = *(const uint4*)(H + (size_t)v * D_H + f);
    bf8_fma(hv, dv * dv, acc);  // self-loop
    float4 b0 = *(const float4*)(bias + f);
    float4 b1 = *(const float4*)(bias + f + 4);
    r[0] = fmaxf(acc[0] + b0.x, 0.f);
    r[1] = fmaxf(acc[1] + b0.y, 0.f);
    r[2] = fmaxf(acc[2] + b0.z, 0.f);
    r[3] = fmaxf(acc[3] + b0.w, 0.f);
    r[4] = fmaxf(acc[4] + b1.x, 0.f);
    r[5] = fmaxf(acc[5] + b1.y, 0.f);
    r[6] = fmaxf(acc[6] + b1.z, 0.f);
    r[7] = fmaxf(acc[7] + b1.w, 0.f);
}

// 4 nodes per block (one per wave)
__global__ __launch_bounds__(256) void gather_agg_relu_bf16(const ushort_t* __restrict__ H,
                                                            const int* __restrict__ deg,
                                                            const int* __restrict__ col,
                                                            const float* __restrict__ dinv,
                                                            const float* __restrict__ bias,
                                                            ushort_t* __restrict__ out) {
    const int v = blockIdx.x * 4 + (threadIdx.x >> 6);
    const int f = (threadIdx.x & 63) * 8;
    float r[8];
    agg_node_bf16(H, deg, col, dinv, bias, v, f, r);
    ushort_t o[8];
#pragma unroll
    for (int i = 0; i < 8; ++i) o[i] = f2b(r[i]);
    *(uint4*)(out + (size_t)v * D_H + f) = *(uint4*)o;
}

// ---------------- segment max pool: node-split partial + reduce ----------------
__global__ __launch_bounds__(256) void pool_max_partial(const ushort_t* __restrict__ h2,
                                                        const int* __restrict__ gstart,
                                                        float* __restrict__ pbuf) {
    const int g = blockIdx.x;
    const int s = blockIdx.y;
    const int f = threadIdx.x * 2;
    const int beg = gstart[g], end = gstart[g + 1];
    const int len = end - beg;
    const int chunk = (len + PSPLIT - 1) / PSPLIT;
    int lo = beg + s * chunk;
    int hi = lo + chunk; if (hi > end) hi = end;
    float m0 = -INFINITY, m1 = -INFINITY;
    int v = lo;
    for (; v + 3 < hi; v += 4) {
        unsigned u0 = *(const unsigned*)(h2 + (size_t)(v + 0) * D_H + f);
        unsigned u1 = *(const unsigned*)(h2 + (size_t)(v + 1) * D_H + f);
        unsigned u2 = *(const unsigned*)(h2 + (size_t)(v + 2) * D_H + f);
        unsigned u3 = *(const unsigned*)(h2 + (size_t)(v + 3) * D_H + f);
        m0 = fmaxf(m0, fmaxf(fmaxf(__uint_as_float(u0 << 16), __uint_as_float(u1 << 16)),
                             fmaxf(__uint_as_float(u2 << 16), __uint_as_float(u3 << 16))));
        m1 = fmaxf(m1, fmaxf(fmaxf(__uint_as_float(u0 & 0xFFFF0000u), __uint_as_float(u1 & 0xFFFF0000u)),
                             fmaxf(__uint_as_float(u2 & 0xFFFF0000u), __uint_as_float(u3 & 0xFFFF0000u))));
    }
    for (; v < hi; ++v) {
        unsigned u = *(const unsigned*)(h2 + (size_t)v * D_H + f);
        m0 = fmaxf(m0, __uint_as_float(u << 16));
        m1 = fmaxf(m1, __uint_as_float(u & 0xFFFF0000u));
    }
    float* p = pbuf + ((size_t)s * N_GRAPHS + g) * D_H + f;
    p[0] = m0;
    p[1] = m1;
}

__global__ void pool_max_final(const float* __restrict__ pbuf, float* __restrict__ gbuf) {
    int i = blockIdx.x * blockDim.x + threadIdx.x;
    if (i >= N_GRAPHS * D_H) return;
    float m = -INFINITY;
#pragma unroll
    for (int s = 0; s < PSPLIT; ++s) m = fmaxf(m, pbuf[(size_t)s * N_GRAPHS * D_H + i]);
    gbuf[i] = m;
}

extern "C" void kernel_launch(void* const* d_in, const int* in_sizes, int n_in,
                              void* d_out, int out_size, void* d_ws, size_t ws_size,
                              hipStream_t stream) {
    const float* x     = (const float*)d_in[0];
    const int*   ei    = (const int*)d_in[1];
    const int*   batch = (const int*)d_in[2];
    const float* Wg1   = (const float*)d_in[3];
    const float* bg1   = (const float*)d_in[4];
    const float* Wg2   = (const float*)d_in[5];
    const float* bg2   = (const float*)d_in[6];
    const float* W1    = (const float*)d_in[7];
    const float* b1    = (const float*)d_in[8];
    const float* W2    = (const float*)d_in[9];
    const float* b2    = (const float*)d_in[10];
    const float* gamma = (const float*)d_in[11];
    const float* beta  = (const float*)d_in[12];
    const int* src = ei;
    const int* dst = ei + N_EDGES;
    float* out = (float*)d_out;

    const int S1 = 8;  // fc1 K-split
    const int S2 = 8;  // fc2 K-split

    // workspace layout (16B-aligned)
    ushort_t* hpre   = (ushort_t*)d_ws;                        // [N_NODES, D_H] bf16
    ushort_t* h1b    = hpre + (size_t)N_NODES * D_H;           // [N_NODES, D_H] bf16
    ushort_t* w1t    = h1b + (size_t)N_NODES * D_H;            // [D_H, D_IN] bf16
    ushort_t* w2t    = w1t + (size_t)D_H * D_IN;               // [D_H, D_H] bf16
    float*    dinv   = (float*)(w2t + (size_t)D_H * D_H);      // [N_NODES]
    float*    gbuf   = dinv + N_NODES;                         // [N_GRAPHS, D_H]
    float*    pbuf   = gbuf + N_GRAPHS * D_H;                  // [PSPLIT, N_GRAPHS, D_H]
    float*    fc1o   = pbuf + (size_t)PSPLIT * N_GRAPHS * D_H; // [N_GRAPHS, D_FC]
    float*    part1  = fc1o + N_GRAPHS * D_FC;                 // [S1, 64, D_FC]
    float*    part2  = part1 + (size_t)S1 * N_GRAPHS * D_FC;   // [S2, 64, OUT_DIMS]
    int*      cursor = (int*)(part2 + (size_t)S2 * N_GRAPHS * OUT_DIMS);  // [N_NODES] -> degree
    int*      colbkt = cursor + N_NODES;                       // [N_NODES * BKT_CAP]
    int*      gstart = colbkt + (size_t)N_NODES * BKT_CAP;     // [N_GRAPHS+1]

    // ---- fused prep: zero cursor + W1^T + W2^T + graph bounds ----
    prep_all<<<PREP_NBLK, 256, 0, stream>>>(Wg1, w1t, Wg2, w2t, cursor, batch, gstart);

    // ---- bucket adjacency build ----
    fill_bucket<<<(N_EDGES + 255) / 256, 256, 0, stream>>>(src, dst, cursor, colbkt);
    compute_dinv<<<(N_NODES + 255) / 256, 256, 0, stream>>>(cursor, dinv);

    const int gconv = 2504;  // 313 row-tiles x 8 col-tiles, 1 wave each

    // conv1: hpre = bf16(x @ Wg1), x consumed as f32 directly ; gather+relu -> h1b
    gemm_dir_af32<<<gconv, 64, 0, stream>>>(x, w1t, hpre, N_NODES, D_H, D_IN);
    gather_agg_relu_bf16<<<N_NODES / 4, 256, 0, stream>>>(hpre, cursor, colbkt, dinv, bg1, h1b);

    // conv2: hpre = bf16(h1b @ Wg2) ; gather+relu -> h2 (reuse h1b) ; pool
    gemm_dir_bf16<<<gconv, 64, 0, stream>>>(h1b, w2t, hpre, N_NODES, D_H, D_H);
    gather_agg_relu_bf16<<<N_NODES / 4, 256, 0, stream>>>(hpre, cursor, colbkt, dinv, bg2, h1b);
    pool_max_partial<<<dim3(N_GRAPHS, PSPLIT), 256, 0, stream>>>(h1b, gstart, pbuf);
    pool_max_final<<<(N_GRAPHS * D_H + 255) / 256, 256, 0, stream>>>(pbuf, gbuf);

    // fc1: [64,512]@[512,1024] split-K=8 -> part1 ; reduce + b1 + relu -> fc1o
    dim3 gfc1((D_FC + 63) / 64, 1, S1);
    gemm_splitk<<<gfc1, 256, 0, stream>>>(gbuf, W1, part1, N_GRAPHS, D_FC, D_H, D_H / S1);
    reduce_bias_relu<<<(N_GRAPHS * D_FC + 255) / 256, 256, 0, stream>>>(
        part1, b1, fc1o, N_GRAPHS * D_FC, D_FC, S1);

    // fc2: [64,1024]@[1024,5000] split-K=8 -> part2 ; reduce + BN + sigmoid -> out
    dim3 gfc2((OUT_DIMS + 63) / 64, 1, S2);
    gemm_splitk<<<gfc2, 256, 0, stream>>>(fc1o, W2, part2, N_GRAPHS, OUT_DIMS, D_FC, D_FC / S2);
    reduce_bn_sigmoid<<<(N_GRAPHS * OUT_DIMS + 255) / 256, 256, 0, stream>>>(
        part2, b2, gamma, beta, out, S2);
}

// Round 9
// 497.317 us; speedup vs baseline: 1.0994x; 1.0994x over previous
//
#include <hip/hip_runtime.h>
#include <math.h>

#define N_NODES 20000
#define N_EDGES 320000
#define N_GRAPHS 64
#define D_IN 1280
#define D_H 512
#define D_FC 1024
#define OUT_DIMS 5000
#define BKT_CAP 64  // max degree capacity (true max ~38 for Poisson(16) over 20k nodes)
#define PSPLIT 8    // pool node-split factor

typedef unsigned short ushort_t;
typedef short bf16x8 __attribute__((ext_vector_type(8)));
typedef float f32x4 __attribute__((ext_vector_type(4)));

__device__ __forceinline__ ushort_t f2b(float x) {
    unsigned u = __float_as_uint(x);
    unsigned r = (u + 0x7FFFu + ((u >> 16) & 1u)) >> 16;  // RNE
    return (ushort_t)r;
}

// packed f32x2 -> bf16x2, RNE (bit-identical to f2b for normal values)
__device__ __forceinline__ unsigned cvt_pk(float lo, float hi) {
    unsigned r;
    asm("v_cvt_pk_bf16_f32 %0, %1, %2" : "=v"(r) : "v"(lo), "v"(hi));
    return r;
}

#define WAITVM(n) asm volatile("s_waitcnt vmcnt(" #n ")" ::: "memory")
#define WAITLG() asm volatile("s_waitcnt lgkmcnt(0)" ::: "memory")

// async 16B global->LDS DMA: per-lane gptr, wave-uniform LDS base (HW adds lane*16)
#define GLL16(gp, lp)                                                                  \
    __builtin_amdgcn_global_load_lds((const __attribute__((address_space(1))) void*)(gp), \
                                     (__attribute__((address_space(3))) void*)(lp), 16, 0, 0)

// ============ 1-wave 64x64 bf16 MFMA GEMM, BK=32, triple-buffered, barrier-free ============
// r7 measured this structure (2 bufs + WAITLG) at 64us/conv1. Triple-buffer removes the
// WAITLG entirely: the buffer DMA'd at iter k ((k+2)%3) was frag-read at iter k-1, and
// those ds_reads retired before iter k-1's MFMAs (program order) -> no lgkm wait needed.
// LDS 24KB -> 6 blocks/CU. Grid 2504 = 313 row-tiles x 8 col-tiles; XCD swizzle.
__global__ __launch_bounds__(64) void gemm_1w_bf16(const ushort_t* __restrict__ A,
                                                   const ushort_t* __restrict__ BT,
                                                   ushort_t* __restrict__ C,
                                                   int M, int N, int K) {
    __shared__ ushort_t lds[12288];  // A bufs: 0,2048,4096 ; B bufs: 6144,8192,10240
    const int lane = threadIdx.x;
    const int lo = lane & 15, quad = lane >> 4;
    const int bid = blockIdx.x;
    const int v = (bid & 7) * 313 + (bid >> 3);  // bijective: 2504 = 8*313
    const int rowBase = (v >> 3) * 64;
    const int colBase = (v & 7) * 64;

    // DMA sources: slot s = lane + 64i -> row (lane>>2)+16i, global chunk q invariant
    const int q = (lane & 3) ^ ((lane >> 3) & 3);
    const int rb = lane >> 2;
    const ushort_t* pa[4];
    const ushort_t* pb[4];
#pragma unroll
    for (int i = 0; i < 4; ++i) {
        int ar = rowBase + rb + 16 * i;
        if (ar >= M) ar = M - 1;  // clamped rows never stored
        pa[i] = A + (size_t)ar * K + q * 8;
        pb[i] = BT + (size_t)(colBase + rb + 16 * i) * K + q * 8;  // N=512 exact
    }

#define ISSUE_TILE(POFF)                                   \
    {                                                      \
        GLL16(pa[0], lds + (POFF) + 0 * 512);              \
        GLL16(pa[1], lds + (POFF) + 1 * 512);              \
        GLL16(pa[2], lds + (POFF) + 2 * 512);              \
        GLL16(pa[3], lds + (POFF) + 3 * 512);              \
        GLL16(pb[0], lds + 6144 + (POFF) + 0 * 512);       \
        GLL16(pb[1], lds + 6144 + (POFF) + 1 * 512);       \
        GLL16(pb[2], lds + 6144 + (POFF) + 2 * 512);       \
        GLL16(pb[3], lds + 6144 + (POFF) + 3 * 512);       \
        pa[0] += 32; pa[1] += 32; pa[2] += 32; pa[3] += 32; \
        pb[0] += 32; pb[1] += 32; pb[2] += 32; pb[3] += 32; \
    }

    const int qs = (quad ^ ((lo >> 1) & 3)) * 8;
    int offA[4], offB[4];
#pragma unroll
    for (int i = 0; i < 4; ++i) offA[i] = (i * 16 + lo) * 32 + qs;
#pragma unroll
    for (int j = 0; j < 4; ++j) offB[j] = (j * 16 + lo) * 32 + qs;

    f32x4 acc[4][4] = {};
    const int NK = K >> 5;

    ISSUE_TILE(0);
    ISSUE_TILE(2048);

    int cur = 0;  // buffer offsets rotate 0 -> 2048 -> 4096 -> 0
    for (int k = 0; k < NK; ++k) {
        if (k + 1 < NK) { WAITVM(8); } else { WAITVM(0); }  // tile k landed, k+1 flying
        const ushort_t* Ab = lds + cur;
        const ushort_t* Bb = lds + 6144 + cur;
        bf16x8 af[4], bfr[4];
#pragma unroll
        for (int i = 0; i < 4; ++i) af[i] = *(const bf16x8*)&Ab[offA[i]];
#pragma unroll
        for (int j = 0; j < 4; ++j) bfr[j] = *(const bf16x8*)&Bb[offB[j]];
        if (k + 2 < NK) {
            int nn = cur + 4096; if (nn >= 6144) nn -= 6144;  // (cur+2)%3 buffer
            ISSUE_TILE(nn);  // overwrites buf read at iter k-1: reads retired pre-MFMA(k-1)
        }
#pragma unroll
        for (int i = 0; i < 4; ++i)
#pragma unroll
            for (int j = 0; j < 4; ++j)
                acc[i][j] = __builtin_amdgcn_mfma_f32_16x16x32_bf16(af[i], bfr[j], acc[i][j], 0, 0, 0);
        cur += 2048; if (cur >= 6144) cur = 0;
    }
#undef ISSUE_TILE

#pragma unroll
    for (int i = 0; i < 4; ++i) {
        int row0 = rowBase + i * 16 + quad * 4;
#pragma unroll
        for (int j = 0; j < 4; ++j) {
            int col = colBase + j * 16 + lo;
            if (col >= N) continue;
#pragma unroll
            for (int r = 0; r < 4; ++r) {
                int row = row0 + r;
                if (row < M) C[(size_t)row * N + col] = f2b(acc[i][j][r]);
            }
        }
    }
}

// ============ 1-wave 64x64 GEMM, A consumed as f32 (conv1), triple-buffered ============
// A: per-lane row loads (lane owns row rowBase+lane, 32 f32 = 8 float4 per tile)
// -> cvt_pk -> 4x ds_write_b128 into the swizzled layout. B: DMA (as above).
// Single wave, no barriers. Ledger: WRITEA(A(k+1)) at iter k dep-waits the A(k+1)
// loads (issued iter k-1) -> vmcnt<=12 -> retires B(k+1) one iter before its frags
// are read => NO explicit WAITVM needed in the loop. One WAITLG at iter top covers
// the previous iter's A ds_writes (issued ~full iter earlier; near-free).
__global__ __launch_bounds__(64) void gemm_1w_af32(const float* __restrict__ A,
                                                   const ushort_t* __restrict__ BT,
                                                   ushort_t* __restrict__ C,
                                                   int M, int N, int K) {
    __shared__ ushort_t lds[12288];  // A bufs: 0,2048,4096 ; B bufs: 6144,8192,10240
    const int lane = threadIdx.x;
    const int lo = lane & 15, quad = lane >> 4;
    const int bid = blockIdx.x;
    const int v = (bid & 7) * 313 + (bid >> 3);
    const int rowBase = (v >> 3) * 64;
    const int colBase = (v & 7) * 64;

    // B DMA mapping
    const int q = (lane & 3) ^ ((lane >> 3) & 3);
    const int rb = lane >> 2;
    const ushort_t* pb[4];
#pragma unroll
    for (int i = 0; i < 4; ++i)
        pb[i] = BT + (size_t)(colBase + rb + 16 * i) * K + q * 8;  // N=512 exact

#define ISSUE_B(POFF)                                      \
    {                                                      \
        GLL16(pb[0], lds + 6144 + (POFF) + 0 * 512);       \
        GLL16(pb[1], lds + 6144 + (POFF) + 1 * 512);       \
        GLL16(pb[2], lds + 6144 + (POFF) + 2 * 512);       \
        GLL16(pb[3], lds + 6144 + (POFF) + 3 * 512);       \
        pb[0] += 32; pb[1] += 32; pb[2] += 32; pb[3] += 32; \
    }

    // A staging: lane owns row rowBase+lane; 4 swizzled chunk writes per tile
    int ar = rowBase + lane; if (ar >= M) ar = M - 1;  // clamped rows never stored
    const float* pA = A + (size_t)ar * K;
    const int swA = (lane >> 1) & 3;
    int wrA[4];
#pragma unroll
    for (int j = 0; j < 4; ++j) wrA[j] = lane * 32 + ((j ^ swA) * 8);

    // two named A f32 register sets (rule #20: static indexing only)
    float4 vA0_0, vA0_1, vA0_2, vA0_3, vA0_4, vA0_5, vA0_6, vA0_7;
    float4 vA1_0, vA1_1, vA1_2, vA1_3, vA1_4, vA1_5, vA1_6, vA1_7;

#define LOADA(S)                                   \
    {                                              \
        vA##S##_0 = *(const float4*)(pA + 0);      \
        vA##S##_1 = *(const float4*)(pA + 4);      \
        vA##S##_2 = *(const float4*)(pA + 8);      \
        vA##S##_3 = *(const float4*)(pA + 12);     \
        vA##S##_4 = *(const float4*)(pA + 16);     \
        vA##S##_5 = *(const float4*)(pA + 20);     \
        vA##S##_6 = *(const float4*)(pA + 24);     \
        vA##S##_7 = *(const float4*)(pA + 28);     \
        pA += 32;                                  \
    }
#define WRITEA(S, POFF)                                                           \
    {                                                                             \
        uint4 u;                                                                  \
        u.x = cvt_pk(vA##S##_0.x, vA##S##_0.y); u.y = cvt_pk(vA##S##_0.z, vA##S##_0.w); \
        u.z = cvt_pk(vA##S##_1.x, vA##S##_1.y); u.w = cvt_pk(vA##S##_1.z, vA##S##_1.w); \
        *(uint4*)&lds[(POFF) + wrA[0]] = u;                                       \
        u.x = cvt_pk(vA##S##_2.x, vA##S##_2.y); u.y = cvt_pk(vA##S##_2.z, vA##S##_2.w); \
        u.z = cvt_pk(vA##S##_3.x, vA##S##_3.y); u.w = cvt_pk(vA##S##_3.z, vA##S##_3.w); \
        *(uint4*)&lds[(POFF) + wrA[1]] = u;                                       \
        u.x = cvt_pk(vA##S##_4.x, vA##S##_4.y); u.y = cvt_pk(vA##S##_4.z, vA##S##_4.w); \
        u.z = cvt_pk(vA##S##_5.x, vA##S##_5.y); u.w = cvt_pk(vA##S##_5.z, vA##S##_5.w); \
        *(uint4*)&lds[(POFF) + wrA[2]] = u;                                       \
        u.x = cvt_pk(vA##S##_6.x, vA##S##_6.y); u.y = cvt_pk(vA##S##_6.z, vA##S##_6.w); \
        u.z = cvt_pk(vA##S##_7.x, vA##S##_7.y); u.w = cvt_pk(vA##S##_7.z, vA##S##_7.w); \
        *(uint4*)&lds[(POFF) + wrA[3]] = u;                                       \
    }

    const int qs = (quad ^ ((lo >> 1) & 3)) * 8;
    int offA[4], offB[4];
#pragma unroll
    for (int i = 0; i < 4; ++i) offA[i] = (i * 16 + lo) * 32 + qs;
#pragma unroll
    for (int j = 0; j < 4; ++j) offB[j] = (j * 16 + lo) * 32 + qs;

    f32x4 acc[4][4] = {};
    const int NK = K >> 5;  // 40 for D_IN (even)

    // prologue: B0, A0(set0), B1, WRITEA(set0->buf0) [dep-wait A0 drains B0], A1(set1)
    ISSUE_B(0);     // B0:4  (oldest)
    LOADA(0);       // A0:8
    ISSUE_B(2048);  // B1:4
    WRITEA(0, 0);   // waits A0 -> vmcnt<=4 -> B0 drained; B1 stays flying
    LOADA(1);       // A1:8

    // body: A(j) in set j&1. At iter k: WRITEA set (k+1)&1, LOADA set k&1 (k+2 = k mod 2).
#define AF32_BODY(kv, SL, SW)                                                          \
    {                                                                                  \
        const int k_ = (kv);                                                           \
        WAITLG(); /* prev iter's A ds_writes drained (issued ~1 iter ago) */           \
        const ushort_t* Ab = lds + cur;                                                \
        const ushort_t* Bb = lds + 6144 + cur;                                         \
        bf16x8 af[4], bfr[4];                                                          \
        _Pragma("unroll") for (int i = 0; i < 4; ++i) af[i] = *(const bf16x8*)&Ab[offA[i]]; \
        _Pragma("unroll") for (int j = 0; j < 4; ++j) bfr[j] = *(const bf16x8*)&Bb[offB[j]]; \
        int nxt = cur + 2048; if (nxt >= 6144) nxt = 0;                                \
        if (k_ + 2 < NK) {                                                             \
            int nn = cur + 4096; if (nn >= 6144) nn -= 6144;                           \
            ISSUE_B(nn);   /* B(k+2):4 */                                              \
            LOADA(SL);     /* A(k+2):8 */                                              \
        }                                                                              \
        if (k_ + 1 < NK) { WRITEA(SW, nxt); } /* dep-wait A(k+1) -> drains B(k+1) */   \
        _Pragma("unroll") for (int i = 0; i < 4; ++i)                                  \
            _Pragma("unroll") for (int j = 0; j < 4; ++j)                              \
                acc[i][j] = __builtin_amdgcn_mfma_f32_16x16x32_bf16(af[i], bfr[j], acc[i][j], 0, 0, 0); \
        cur = nxt;                                                                     \
    }

    int cur = 0;
    for (int kk = 0; kk < NK; kk += 2) {
        AF32_BODY(kk, 0, 1);
        AF32_BODY(kk + 1, 1, 0);
    }
#undef AF32_BODY
#undef ISSUE_B
#undef LOADA
#undef WRITEA

#pragma unroll
    for (int i = 0; i < 4; ++i) {
        int row0 = rowBase + i * 16 + quad * 4;
#pragma unroll
        for (int j = 0; j < 4; ++j) {
            int col = colBase + j * 16 + lo;
            if (col >= N) continue;
#pragma unroll
            for (int r = 0; r < 4; ++r) {
                int row = row0 + r;
                if (row < M) C[(size_t)row * N + col] = f2b(acc[i][j][r]);
            }
        }
    }
}

// ================= fused prep kernel (no x conversion) =================
#define PREP_ZB 5
#define PREP_T1 640
#define PREP_T2 256
#define PREP_NBLK (PREP_ZB + PREP_T1 + PREP_T2 + 1)

__global__ __launch_bounds__(256) void prep_all(const float* __restrict__ W1src, ushort_t* __restrict__ w1t,
                                                const float* __restrict__ W2src, ushort_t* __restrict__ w2t,
                                                int* __restrict__ zbase,  // cursor
                                                const int* __restrict__ batch, int* __restrict__ gstart) {
    __shared__ float tile[32][33];
    int b = blockIdx.x;
    const int t = threadIdx.x;

    if (b < PREP_ZB) {  // zero 20000 ints
        int i = b * 256 + t;
        if (i < 1250) {
            int4* p = (int4*)zbase + (size_t)i * 4;
            int4 z = {0, 0, 0, 0};
            p[0] = z; p[1] = z; p[2] = z; p[3] = z;
        }
        return;
    }
    b -= PREP_ZB;

    if (b < PREP_T1 + PREP_T2) {  // tiled transpose + cvt
        const float* W;
        ushort_t* WT;
        int K, N, tb;
        if (b < PREP_T1) { W = W1src; WT = w1t; K = D_IN; N = D_H; tb = b; }
        else             { W = W2src; WT = w2t; K = D_H;  N = D_H; tb = b - PREP_T1; }
        const int ntn = N >> 5;
        const int kt = tb / ntn, nt = tb - kt * ntn;
        const int tx = t & 31, ty = t >> 5;
#pragma unroll
        for (int it = 0; it < 4; ++it) {
            int k = kt * 32 + ty + it * 8;
            tile[ty + it * 8][tx] = W[(size_t)k * N + nt * 32 + tx];
        }
        __syncthreads();
#pragma unroll
        for (int it = 0; it < 4; ++it) {
            int n = nt * 32 + ty + it * 8;
            WT[(size_t)n * K + kt * 32 + tx] = f2b(tile[tx][ty + it * 8]);
        }
        return;
    }

    // graph_bounds
    if (t <= N_GRAPHS) {
        int lo = 0, hi = N_NODES;
        while (lo < hi) {
            int mid = (lo + hi) >> 1;
            if (batch[mid] < t) lo = mid + 1; else hi = mid;
        }
        gstart[t] = lo;
    }
}

// ---------------- bucket CSR (no scan): col[d*64+p] ----------------
__global__ void fill_bucket(const int* __restrict__ src, const int* __restrict__ dst,
                            int* __restrict__ cursor, int* __restrict__ col) {
    int e = blockIdx.x * blockDim.x + threadIdx.x;
    if (e < N_EDGES) {
        int d = dst[e];
        int p = atomicAdd(cursor + d, 1);
        if (p < BKT_CAP) col[(d << 6) + p] = src[e];
    }
}

// dinv = rsqrt(true_degree + 1); cursor holds true degree after fill_bucket
__global__ void compute_dinv(const int* __restrict__ deg, float* __restrict__ dinv) {
    int v = blockIdx.x * blockDim.x + threadIdx.x;
    if (v < N_NODES) dinv[v] = rsqrtf((float)deg[v] + 1.0f);
}

// ---------------- fp32 split-K tiled GEMM (FC head) ----------------
__global__ __launch_bounds__(256) void gemm_splitk(const float* __restrict__ A,
                                                   const float* __restrict__ B,
                                                   float* __restrict__ P,
                                                   int M, int N, int K, int KC) {
    __shared__ float As[16][64];
    __shared__ float Bs[16][64];
    const int t = threadIdx.x;
    const int tx = t & 15, ty = t >> 4;
    const int rowBase = blockIdx.y * 64;
    const int colBase = blockIdx.x * 64;
    const int kbeg = blockIdx.z * KC;
    const int kend = kbeg + KC;
    float acc[4][4] = {};
    for (int k0 = kbeg; k0 < kend; k0 += 16) {
#pragma unroll
        for (int i = 0; i < 4; ++i) {
            int idx = t + i * 256;
            int row = idx >> 4, kk = idx & 15;
            int gr = rowBase + row;
            As[kk][row] = (gr < M) ? A[(size_t)gr * K + k0 + kk] : 0.f;
        }
#pragma unroll
        for (int i = 0; i < 4; ++i) {
            int idx = t + i * 256;
            int kk = idx >> 6, col = idx & 63;
            int gc = colBase + col;
            Bs[kk][col] = (gc < N) ? B[(size_t)(k0 + kk) * N + gc] : 0.f;
        }
        __syncthreads();
#pragma unroll
        for (int kk = 0; kk < 16; ++kk) {
            float a[4], bb[4];
#pragma unroll
            for (int i = 0; i < 4; ++i) a[i] = As[kk][ty * 4 + i];
#pragma unroll
            for (int j = 0; j < 4; ++j) bb[j] = Bs[kk][tx * 4 + j];
#pragma unroll
            for (int i = 0; i < 4; ++i)
#pragma unroll
                for (int j = 0; j < 4; ++j) acc[i][j] = fmaf(a[i], bb[j], acc[i][j]);
        }
        __syncthreads();
    }
    float* Pz = P + (size_t)blockIdx.z * M * N;
#pragma unroll
    for (int i = 0; i < 4; ++i) {
        int gr = rowBase + ty * 4 + i;
        if (gr >= M) continue;
#pragma unroll
        for (int j = 0; j < 4; ++j) {
            int gc = colBase + tx * 4 + j;
            if (gc < N) Pz[(size_t)gr * N + gc] = acc[i][j];
        }
    }
}

__global__ void reduce_bias_relu(const float* __restrict__ P, const float* __restrict__ b,
                                 float* __restrict__ out, int total, int N, int S) {
    int i = blockIdx.x * blockDim.x + threadIdx.x;
    if (i >= total) return;
    float s = 0.f;
    for (int z = 0; z < S; ++z) s += P[(size_t)z * total + i];
    out[i] = fmaxf(s + b[i % N], 0.f);
}

__global__ void reduce_bn_sigmoid(const float* __restrict__ P, const float* __restrict__ b2,
                                  const float* __restrict__ gamma, const float* __restrict__ beta,
                                  float* __restrict__ out, int S) {
    int i = blockIdx.x * blockDim.x + threadIdx.x;
    if (i >= N_GRAPHS * OUT_DIMS) return;
    int c = i % OUT_DIMS;
    float s = 0.f;
    for (int z = 0; z < S; ++z) s += P[(size_t)z * N_GRAPHS * OUT_DIMS + i];
    const float sc = 0.9999950000374997f;  // 1/sqrt(1+1e-5)
    float zz = (s + b2[c]) * (gamma[c] * sc) + beta[c];
    out[i] = 1.f / (1.f + expf(-zz));
}

// ---------------- bf16 gather-aggregate ----------------
__device__ __forceinline__ void bf8_fma(uint4 v, float c, float* acc) {
    unsigned a[4] = {v.x, v.y, v.z, v.w};
#pragma unroll
    for (int i = 0; i < 4; ++i) {
        float lo = __uint_as_float(a[i] << 16);
        float hi = __uint_as_float(a[i] & 0xFFFF0000u);
        acc[2 * i]     = fmaf(lo, c, acc[2 * i]);
        acc[2 * i + 1] = fmaf(hi, c, acc[2 * i + 1]);
    }
}

__device__ __forceinline__ void agg_node_bf16(const ushort_t* __restrict__ H,
                                              const int* __restrict__ deg,
                                              const int* __restrict__ col,
                                              const float* __restrict__ dinv,
                                              const float* __restrict__ bias,
                                              int v, int f, float* r) {
    const int beg = v << 6;
    int d = deg[v]; if (d > BKT_CAP) d = BKT_CAP;
    const int end = beg + d;
    const float dv = dinv[v];
    float acc[8] = {};
    int j = beg;
    for (; j + 7 < end; j += 8) {
        int s[8];
#pragma unroll
        for (int u = 0; u < 8; ++u) s[u] = col[j + u];
        float c[8];
#pragma unroll
        for (int u = 0; u < 8; ++u) c[u] = dinv[s[u]] * dv;
        uint4 h[8];
#pragma unroll
        for (int u = 0; u < 8; ++u) h[u] = *(const uint4*)(H + (size_t)s[u] * D_H + f);
#pragma unroll
        for (int u = 0; u < 8; ++u) bf8_fma(h[u], c[u], acc);
    }
    for (; j + 3 < end; j += 4) {
        int s0 = col[j], s1 = col[j + 1], s2 = col[j + 2], s3 = col[j + 3];
        float c0 = dinv[s0] * dv, c1 = dinv[s1] * dv;
        float c2 = dinv[s2] * dv, c3 = dinv[s3] * dv;
        uint4 h0 = *(const uint4*)(H + (size_t)s0 * D_H + f);
        uint4 h1 = *(const uint4*)(H + (size_t)s1 * D_H + f);
        uint4 h2 = *(const uint4*)(H + (size_t)s2 * D_H + f);
        uint4 h3 = *(const uint4*)(H + (size_t)s3 * D_H + f);
        bf8_fma(h0, c0, acc);
        bf8_fma(h1, c1, acc);
        bf8_fma(h2, c2, acc);
        bf8_fma(h3, c3, acc);
    }
    for (; j < end; ++j) {
        int s0 = col[j];
        float c0 = dinv[s0] * dv;
        uint4 h0 = *(const uint4*)(H + (size_t)s0 * D_H + f);
        bf8_fma(h0, c0, acc);
    }
    uint4 hv = *(const uint4*)(H + (size_t)v * D_H + f);
    bf8_fma(hv, dv * dv, acc);  // self-loop
    float4 b0 = *(const float4*)(bias + f);
    float4 b1 = *(const float4*)(bias + f + 4);
    r[0] = fmaxf(acc[0] + b0.x, 0.f);
    r[1] = fmaxf(acc[1] + b0.y, 0.f);
    r[2] = fmaxf(acc[2] + b0.z, 0.f);
    r[3] = fmaxf(acc[3] + b0.w, 0.f);
    r[4] = fmaxf(acc[4] + b1.x, 0.f);
    r[5] = fmaxf(acc[5] + b1.y, 0.f);
    r[6] = fmaxf(acc[6] + b1.z, 0.f);
    r[7] = fmaxf(acc[7] + b1.w, 0.f);
}

// 4 nodes per block (one per wave)
__global__ __launch_bounds__(256) void gather_agg_relu_bf16(const ushort_t* __restrict__ H,
                                                            const int* __restrict__ deg,
                                                            const int* __restrict__ col,
                                                            const float* __restrict__ dinv,
                                                            const float* __restrict__ bias,
                                                            ushort_t* __restrict__ out) {
    const int v = blockIdx.x * 4 + (threadIdx.x >> 6);
    const int f = (threadIdx.x & 63) * 8;
    float r[8];
    agg_node_bf16(H, deg, col, dinv, bias, v, f, r);
    ushort_t o[8];
#pragma unroll
    for (int i = 0; i < 8; ++i) o[i] = f2b(r[i]);
    *(uint4*)(out + (size_t)v * D_H + f) = *(uint4*)o;
}

// ---------------- segment max pool: node-split partial + reduce ----------------
__global__ __launch_bounds__(256) void pool_max_partial(const ushort_t* __restrict__ h2,
                                                        const int* __restrict__ gstart,
                                                        float* __restrict__ pbuf) {
    const int g = blockIdx.x;
    const int s = blockIdx.y;
    const int f = threadIdx.x * 2;
    const int beg = gstart[g], end = gstart[g + 1];
    const int len = end - beg;
    const int chunk = (len + PSPLIT - 1) / PSPLIT;
    int lo = beg + s * chunk;
    int hi = lo + chunk; if (hi > end) hi = end;
    float m0 = -INFINITY, m1 = -INFINITY;
    int v = lo;
    for (; v + 3 < hi; v += 4) {
        unsigned u0 = *(const unsigned*)(h2 + (size_t)(v + 0) * D_H + f);
        unsigned u1 = *(const unsigned*)(h2 + (size_t)(v + 1) * D_H + f);
        unsigned u2 = *(const unsigned*)(h2 + (size_t)(v + 2) * D_H + f);
        unsigned u3 = *(const unsigned*)(h2 + (size_t)(v + 3) * D_H + f);
        m0 = fmaxf(m0, fmaxf(fmaxf(__uint_as_float(u0 << 16), __uint_as_float(u1 << 16)),
                             fmaxf(__uint_as_float(u2 << 16), __uint_as_float(u3 << 16))));
        m1 = fmaxf(m1, fmaxf(fmaxf(__uint_as_float(u0 & 0xFFFF0000u), __uint_as_float(u1 & 0xFFFF0000u)),
                             fmaxf(__uint_as_float(u2 & 0xFFFF0000u), __uint_as_float(u3 & 0xFFFF0000u))));
    }
    for (; v < hi; ++v) {
        unsigned u = *(const unsigned*)(h2 + (size_t)v * D_H + f);
        m0 = fmaxf(m0, __uint_as_float(u << 16));
        m1 = fmaxf(m1, __uint_as_float(u & 0xFFFF0000u));
    }
    float* p = pbuf + ((size_t)s * N_GRAPHS + g) * D_H + f;
    p[0] = m0;
    p[1] = m1;
}

__global__ void pool_max_final(const float* __restrict__ pbuf, float* __restrict__ gbuf) {
    int i = blockIdx.x * blockDim.x + threadIdx.x;
    if (i >= N_GRAPHS * D_H) return;
    float m = -INFINITY;
#pragma unroll
    for (int s = 0; s < PSPLIT; ++s) m = fmaxf(m, pbuf[(size_t)s * N_GRAPHS * D_H + i]);
    gbuf[i] = m;
}

extern "C" void kernel_launch(void* const* d_in, const int* in_sizes, int n_in,
                              void* d_out, int out_size, void* d_ws, size_t ws_size,
                              hipStream_t stream) {
    const float* x     = (const float*)d_in[0];
    const int*   ei    = (const int*)d_in[1];
    const int*   batch = (const int*)d_in[2];
    const float* Wg1   = (const float*)d_in[3];
    const float* bg1   = (const float*)d_in[4];
    const float* Wg2   = (const float*)d_in[5];
    const float* bg2   = (const float*)d_in[6];
    const float* W1    = (const float*)d_in[7];
    const float* b1    = (const float*)d_in[8];
    const float* W2    = (const float*)d_in[9];
    const float* b2    = (const float*)d_in[10];
    const float* gamma = (const float*)d_in[11];
    const float* beta  = (const float*)d_in[12];
    const int* src = ei;
    const int* dst = ei + N_EDGES;
    float* out = (float*)d_out;

    const int S1 = 8;  // fc1 K-split
    const int S2 = 8;  // fc2 K-split

    // workspace layout (16B-aligned)
    ushort_t* hpre   = (ushort_t*)d_ws;                        // [N_NODES, D_H] bf16
    ushort_t* h1b    = hpre + (size_t)N_NODES * D_H;           // [N_NODES, D_H] bf16
    ushort_t* w1t    = h1b + (size_t)N_NODES * D_H;            // [D_H, D_IN] bf16
    ushort_t* w2t    = w1t + (size_t)D_H * D_IN;               // [D_H, D_H] bf16
    float*    dinv   = (float*)(w2t + (size_t)D_H * D_H);      // [N_NODES]
    float*    gbuf   = dinv + N_NODES;                         // [N_GRAPHS, D_H]
    float*    pbuf   = gbuf + N_GRAPHS * D_H;                  // [PSPLIT, N_GRAPHS, D_H]
    float*    fc1o   = pbuf + (size_t)PSPLIT * N_GRAPHS * D_H; // [N_GRAPHS, D_FC]
    float*    part1  = fc1o + N_GRAPHS * D_FC;                 // [S1, 64, D_FC]
    float*    part2  = part1 + (size_t)S1 * N_GRAPHS * D_FC;   // [S2, 64, OUT_DIMS]
    int*      cursor = (int*)(part2 + (size_t)S2 * N_GRAPHS * OUT_DIMS);  // [N_NODES] -> degree
    int*      colbkt = cursor + N_NODES;                       // [N_NODES * BKT_CAP]
    int*      gstart = colbkt + (size_t)N_NODES * BKT_CAP;     // [N_GRAPHS+1]

    // ---- fused prep: zero cursor + W1^T + W2^T + graph bounds ----
    prep_all<<<PREP_NBLK, 256, 0, stream>>>(Wg1, w1t, Wg2, w2t, cursor, batch, gstart);

    // ---- bucket adjacency build ----
    fill_bucket<<<(N_EDGES + 255) / 256, 256, 0, stream>>>(src, dst, cursor, colbkt);
    compute_dinv<<<(N_NODES + 255) / 256, 256, 0, stream>>>(cursor, dinv);

    const int gconv = 2504;  // 313 row-tiles x 8 col-tiles, 1 wave each

    // conv1: hpre = bf16(x @ Wg1), x consumed as f32 in-kernel ; gather+relu -> h1b
    gemm_1w_af32<<<gconv, 64, 0, stream>>>(x, w1t, hpre, N_NODES, D_H, D_IN);
    gather_agg_relu_bf16<<<N_NODES / 4, 256, 0, stream>>>(hpre, cursor, colbkt, dinv, bg1, h1b);

    // conv2: hpre = bf16(h1b @ Wg2) ; gather+relu -> h2 (reuse h1b) ; pool
    gemm_1w_bf16<<<gconv, 64, 0, stream>>>(h1b, w2t, hpre, N_NODES, D_H, D_H);
    gather_agg_relu_bf16<<<N_NODES / 4, 256, 0, stream>>>(hpre, cursor, colbkt, dinv, bg2, h1b);
    pool_max_partial<<<dim3(N_GRAPHS, PSPLIT), 256, 0, stream>>>(h1b, gstart, pbuf);
    pool_max_final<<<(N_GRAPHS * D_H + 255) / 256, 256, 0, stream>>>(pbuf, gbuf);

    // fc1: [64,512]@[512,1024] split-K=8 -> part1 ; reduce + b1 + relu -> fc1o
    dim3 gfc1((D_FC + 63) / 64, 1, S1);
    gemm_splitk<<<gfc1, 256, 0, stream>>>(gbuf, W1, part1, N_GRAPHS, D_FC, D_H, D_H / S1);
    reduce_bias_relu<<<(N_GRAPHS * D_FC + 255) / 256, 256, 0, stream>>>(
        part1, b1, fc1o, N_GRAPHS * D_FC, D_FC, S1);

    // fc2: [64,1024]@[1024,5000] split-K=8 -> part2 ; reduce + BN + sigmoid -> out
    dim3 gfc2((OUT_DIMS + 63) / 64, 1, S2);
    gemm_splitk<<<gfc2, 256, 0, stream>>>(fc1o, W2, part2, N_GRAPHS, OUT_DIMS, D_FC, D_FC / S2);
    reduce_bn_sigmoid<<<(N_GRAPHS * OUT_DIMS + 255) / 256, 256, 0, stream>>>(
        part2, b2, gamma, beta, out, S2);
}